// Round 1
// baseline (703.864 us; speedup 1.0000x reference)
//
#include <hip/hip_runtime.h>
#include <hip/hip_bf16.h>

// GCN 2-layer on MI355X.
// Pipeline: detect dtypes -> degree count -> exclusive scan (CSR starts) ->
// scatter edges into CSR -> GEMM h=x@W1 -> wave-per-node aggregation+epilogue
// (layer1 fused with layer2 GEMV) -> wave-per-node scalar aggregation (layer2).
// No float atomics anywhere; accumulation in registers via CSR.

__device__ __forceinline__ float bf2f(unsigned short u) {
    union { unsigned int u; float f; } c; c.u = ((unsigned int)u) << 16; return c.f;
}
__device__ __forceinline__ unsigned short f2bf(float f) {
    union { float f; unsigned int u; } c; c.f = f;
    unsigned int u = c.u;
    unsigned int r = (u + 0x7fffu + ((u >> 16) & 1u)) >> 16;  // round-nearest-even
    return (unsigned short)r;
}
// Load a "float tensor" element that may be bf16 or f32 depending on runtime flag.
__device__ __forceinline__ float loadF(const void* p, int i, int isbf) {
    return isbf ? bf2f(((const unsigned short*)p)[i]) : ((const float*)p)[i];
}
// Load an edge index that may be int64 or int32.
__device__ __forceinline__ int edgeIdx(const void* e, long long i, int is64) {
    return is64 ? (int)((const long long*)e)[i] : ((const int*)e)[i];
}

// flags[0] = edge indices are int64; flags[1] = float tensors are bf16
__global__ void k_detect(const void* e, const void* x, int* flags) {
    int lane = threadIdx.x;  // blockDim = 64
    // int64 check: for int64 values < 2^31, every odd 32-bit word is 0.
    unsigned int ew = ((const unsigned int*)e)[2 * lane + 1];
    unsigned long long nz = __ballot(ew != 0);
    // bf16 check: low 16 bits of each 32-bit word are a bf16 of an N(0,1) value
    // (exponent in a narrow band) iff packed bf16; for f32 they're uniform mantissa bits.
    unsigned int xw = ((const unsigned int*)x)[lane];
    unsigned int low = xw & 0xffffu;
    unsigned int e8 = (low >> 7) & 0xffu;
    bool plaus = (low == 0u) || (e8 >= 110u && e8 <= 135u);
    unsigned long long pl = __ballot(plaus);
    if (lane == 0) {
        flags[0] = (nz == 0ull) ? 1 : 0;
        flags[1] = (__popcll(pl) > 32) ? 1 : 0;
    }
}

__global__ void k_count(const void* e, int* deg, const int* flags, int E) {
    int i = blockIdx.x * blockDim.x + threadIdx.x;
    int is64 = flags[0];
    if (i < E) {
        int d = edgeIdx(e, (long long)E + i, is64);
        atomicAdd(&deg[d], 1);
    }
}

__global__ void k_scanA(const int* deg, int* start, int* blkSum, int N) {
    __shared__ int s[256];
    int tid = threadIdx.x;
    int i = blockIdx.x * 256 + tid;
    int v = (i < N) ? deg[i] : 0;
    s[tid] = v; __syncthreads();
    for (int off = 1; off < 256; off <<= 1) {
        int t = (tid >= off) ? s[tid - off] : 0;
        __syncthreads();
        s[tid] += t;
        __syncthreads();
    }
    if (i < N) start[i] = s[tid] - v;  // exclusive within block
    if (tid == 255) blkSum[blockIdx.x] = s[255];
}

__global__ void k_scanB(const int* blkSum, int* blkOff, int nb) {
    __shared__ int s[512];
    int tid = threadIdx.x;
    int v = (tid < nb) ? blkSum[tid] : 0;
    s[tid] = v; __syncthreads();
    for (int off = 1; off < 512; off <<= 1) {
        int t = (tid >= off) ? s[tid - off] : 0;
        __syncthreads();
        s[tid] += t;
        __syncthreads();
    }
    blkOff[tid] = s[tid] - v;  // exclusive
}

__global__ void k_scanC(int* start, const int* blkOff, const int* deg,
                        int* cursor, float* dinv, int N) {
    int i = blockIdx.x * blockDim.x + threadIdx.x;
    if (i < N) {
        start[i] += blkOff[i >> 8];
        cursor[i] = 0;
        dinv[i] = rsqrtf((float)(deg[i] + 1));  // +1 self-loop; deg>=1 always
    }
}

__global__ void k_scatter(const void* e, const int* start, int* cursor,
                          int* srcSorted, const int* flags, int E) {
    int i = blockIdx.x * blockDim.x + threadIdx.x;
    int is64 = flags[0];
    if (i < E) {
        int s = edgeIdx(e, i, is64);
        int d = edgeIdx(e, (long long)E + i, is64);
        int pos = start[d] + atomicAdd(&cursor[d], 1);
        srcSorted[pos] = s;
    }
}

// h[N,64] = x[N,128] @ W1[128,64], f32 accumulate, f32 out to workspace.
__launch_bounds__(256)
__global__ void k_gemm(const void* x, const void* W1, float* __restrict__ h,
                       const int* flags, int N) {
    __shared__ float Wl[128 * 64];   // 32 KB
    __shared__ float xr[4][128];     // one staged row per wave
    int tid = threadIdx.x;
    int isbf = flags[1];
    for (int idx = tid; idx < 128 * 64; idx += 256) Wl[idx] = loadF(W1, idx, isbf);
    int w = tid >> 6, lane = tid & 63;
    for (int rb = blockIdx.x * 4; rb < N; rb += gridDim.x * 4) {
        int row = rb + w;
        bool active = row < N;
        __syncthreads();  // xr from prev iter fully consumed; W loaded (1st iter)
        if (active) {
            if (isbf) {
                unsigned int wv = ((const unsigned int*)x)[(long long)row * 64 + lane];
                xr[w][2 * lane]     = bf2f((unsigned short)(wv & 0xffffu));
                xr[w][2 * lane + 1] = bf2f((unsigned short)(wv >> 16));
            } else {
                xr[w][lane]      = ((const float*)x)[(long long)row * 128 + lane];
                xr[w][lane + 64] = ((const float*)x)[(long long)row * 128 + 64 + lane];
            }
        }
        __syncthreads();
        if (active) {
            float acc = 0.f;
            #pragma unroll
            for (int k = 0; k < 128; ++k)
                acc += xr[w][k] * Wl[k * 64 + lane];  // broadcast + 2-way bank (free)
            h[(long long)row * 64 + lane] = acc;
        }
    }
}

// Layer-1 aggregation + epilogue (bias, relu, dot W2, scale dinv) fused.
// One wave per node; lane = feature. sbuf2[i] = (relu(agg+b1)·W2) * dinv[i].
__launch_bounds__(256)
__global__ void k_agg1(const float* __restrict__ h, const float* __restrict__ dinv,
                       const int* __restrict__ start, const int* __restrict__ deg,
                       const int* __restrict__ srcSorted,
                       const void* b1, const void* W2, float* __restrict__ sbuf2,
                       const int* flags, int N) {
    int lane = threadIdx.x & 63;
    int node = (blockIdx.x * blockDim.x + threadIdx.x) >> 6;
    if (node >= N) return;
    int isbf = flags[1];
    float di = dinv[node];
    float acc = h[(long long)node * 64 + lane] * di * di;  // self-loop
    int base = start[node], cnt = deg[node];
    for (int c = 0; c < cnt; c += 64) {
        int t = c + lane;
        int sidx = 0; float dv = 0.f;
        if (t < cnt) { sidx = srcSorted[base + t]; dv = dinv[sidx]; }
        int m = cnt - c; if (m > 64) m = 64;
        for (int t2 = 0; t2 < m; ++t2) {
            int s2 = __shfl(sidx, t2);
            float wgt = __shfl(dv, t2) * di;
            acc += h[(long long)s2 * 64 + lane] * wgt;
        }
    }
    float v = acc + loadF(b1, lane, isbf);
    v = fmaxf(v, 0.f);
    float p = v * loadF(W2, lane, isbf);
    #pragma unroll
    for (int o = 32; o >= 1; o >>= 1) p += __shfl_xor(p, o);
    if (lane == 0) sbuf2[node] = p * di;
}

// Layer-2 scalar aggregation: out[i] = (sum_in sbuf2[src] + sbuf2[i]) * dinv[i] + b2
__launch_bounds__(256)
__global__ void k_agg2(const float* __restrict__ sbuf2, const float* __restrict__ dinv,
                       const int* __restrict__ start, const int* __restrict__ deg,
                       const int* __restrict__ srcSorted,
                       const void* b2, void* out, const int* flags, int N) {
    int lane = threadIdx.x & 63;
    int node = (blockIdx.x * blockDim.x + threadIdx.x) >> 6;
    if (node >= N) return;
    int isbf = flags[1];
    float di = dinv[node];
    int base = start[node], cnt = deg[node];
    float part = 0.f;
    for (int t = lane; t < cnt; t += 64) part += sbuf2[srcSorted[base + t]];
    #pragma unroll
    for (int o = 32; o >= 1; o >>= 1) part += __shfl_xor(part, o);
    if (lane == 0) {
        float o_ = (part + sbuf2[node]) * di + loadF(b2, 0, isbf);
        if (isbf) ((unsigned short*)out)[node] = f2bf(o_);
        else      ((float*)out)[node] = o_;
    }
}

extern "C" void kernel_launch(void* const* d_in, const int* in_sizes, int n_in,
                              void* d_out, int out_size, void* d_ws, size_t ws_size,
                              hipStream_t stream) {
    const void* x  = d_in[0];
    const void* e  = d_in[1];
    const void* W1 = d_in[2];
    const void* b1 = d_in[3];
    const void* W2 = d_in[4];
    const void* b2 = d_in[5];
    int N = in_sizes[0] / 128;   // 100000
    int E = in_sizes[1] / 2;     // 3200000
    int nb = (N + 255) / 256;    // 391 (must be <= 512 for scanB)
    int NP = nb * 256;

    int*   wsI       = (int*)d_ws;
    int*   flags     = wsI;                 // 256 ints
    int*   deg       = wsI + 256;           // NP
    int*   start     = deg + NP;            // NP
    int*   cursor    = start + NP;          // NP
    float* dinv      = (float*)(cursor + NP);   // NP
    float* sbuf2     = dinv + NP;               // NP
    int*   blkSum    = (int*)(sbuf2 + NP);  // 512
    int*   blkOff    = blkSum + 512;        // 512
    int*   srcSorted = blkOff + 512;        // E (rounded)
    float* h         = (float*)(srcSorted + ((E + 255) / 256) * 256);  // N*64

    hipMemsetAsync(deg, 0, (size_t)NP * sizeof(int), stream);
    hipLaunchKernelGGL(k_detect, dim3(1), dim3(64), 0, stream, e, x, flags);
    hipLaunchKernelGGL(k_count, dim3((E + 255) / 256), dim3(256), 0, stream,
                       e, deg, flags, E);
    hipLaunchKernelGGL(k_scanA, dim3(nb), dim3(256), 0, stream, deg, start, blkSum, N);
    hipLaunchKernelGGL(k_scanB, dim3(1), dim3(512), 0, stream, blkSum, blkOff, nb);
    hipLaunchKernelGGL(k_scanC, dim3(nb), dim3(256), 0, stream,
                       start, blkOff, deg, cursor, dinv, N);
    hipLaunchKernelGGL(k_scatter, dim3((E + 255) / 256), dim3(256), 0, stream,
                       e, start, cursor, srcSorted, flags, E);
    hipLaunchKernelGGL(k_gemm, dim3(2048), dim3(256), 0, stream, x, W1, h, flags, N);
    hipLaunchKernelGGL(k_agg1, dim3((N + 3) / 4), dim3(256), 0, stream,
                       h, dinv, start, deg, srcSorted, b1, W2, sbuf2, flags, N);
    hipLaunchKernelGGL(k_agg2, dim3((N + 3) / 4), dim3(256), 0, stream,
                       sbuf2, dinv, start, deg, srcSorted, b2, d_out, flags, N);
}

// Round 3
// 587.634 us; speedup vs baseline: 1.1978x; 1.1978x over previous
//
#include <hip/hip_runtime.h>
#include <hip/hip_bf16.h>

// GCN 2-layer on MI355X.
// Pipeline: detect dtypes -> degree count + per-edge rank (atomic return) ->
// exclusive scan (CSR starts) -> atomic-free scatter into CSR -> GEMM h=x@W1 ->
// wave-per-node aggregation+epilogue (layer1 fused with layer2 GEMV) ->
// wave-per-node scalar aggregation (layer2).
// R2: rank trick + 8-way ILP in count/scatter (R1: scatter 220us, VALUBusy 0.5%,
// classic 1-outstanding-op latency wall).
// R3: R2 crashed = d_ws overflow (rank grew ws to 52.8MB vs R1's proven 40.4MB).
//     Fix: alias rank[] into the h[] region (h first written by k_gemm, strictly
//     after k_scatter consumes rank). Footprint back to 40.0MB.

__device__ __forceinline__ float bf2f(unsigned short u) {
    union { unsigned int u; float f; } c; c.u = ((unsigned int)u) << 16; return c.f;
}
__device__ __forceinline__ unsigned short f2bf(float f) {
    union { float f; unsigned int u; } c; c.f = f;
    unsigned int u = c.u;
    unsigned int r = (u + 0x7fffu + ((u >> 16) & 1u)) >> 16;  // round-nearest-even
    return (unsigned short)r;
}
__device__ __forceinline__ float loadF(const void* p, int i, int isbf) {
    return isbf ? bf2f(((const unsigned short*)p)[i]) : ((const float*)p)[i];
}
__device__ __forceinline__ int edgeIdx(const void* e, long long i, int is64) {
    return is64 ? (int)((const long long*)e)[i] : ((const int*)e)[i];
}

// flags[0] = edge indices are int64; flags[1] = float tensors are bf16
__global__ void k_detect(const void* e, const void* x, int* flags) {
    int lane = threadIdx.x;  // blockDim = 64
    unsigned int ew = ((const unsigned int*)e)[2 * lane + 1];
    unsigned long long nz = __ballot(ew != 0);
    unsigned int xw = ((const unsigned int*)x)[lane];
    unsigned int low = xw & 0xffffu;
    unsigned int e8 = (low >> 7) & 0xffu;
    bool plaus = (low == 0u) || (e8 >= 110u && e8 <= 135u);
    unsigned long long pl = __ballot(plaus);
    if (lane == 0) {
        flags[0] = (nz == 0ull) ? 1 : 0;
        flags[1] = (__popcll(pl) > 32) ? 1 : 0;
    }
}

// Degree histogram + unique per-edge rank within its dst group.
// 8 edges/thread (grid-stride, unrolled) -> 8 independent atomics in flight.
__launch_bounds__(256)
__global__ void k_count(const void* e, int* __restrict__ deg, int* __restrict__ rank,
                        const int* flags, int E) {
    int is64 = flags[0];
    int gsz = gridDim.x * blockDim.x;
    int i0 = blockIdx.x * blockDim.x + threadIdx.x;
    #pragma unroll
    for (int k = 0; k < 8; ++k) {
        int i = i0 + k * gsz;
        if (i < E) {
            int d = edgeIdx(e, (long long)E + i, is64);
            rank[i] = atomicAdd(&deg[d], 1);
        }
    }
}

__global__ void k_scanA(const int* deg, int* start, int* blkSum, int N) {
    __shared__ int s[256];
    int tid = threadIdx.x;
    int i = blockIdx.x * 256 + tid;
    int v = (i < N) ? deg[i] : 0;
    s[tid] = v; __syncthreads();
    for (int off = 1; off < 256; off <<= 1) {
        int t = (tid >= off) ? s[tid - off] : 0;
        __syncthreads();
        s[tid] += t;
        __syncthreads();
    }
    if (i < N) start[i] = s[tid] - v;  // exclusive within block
    if (tid == 255) blkSum[blockIdx.x] = s[255];
}

__global__ void k_scanB(const int* blkSum, int* blkOff, int nb) {
    __shared__ int s[512];
    int tid = threadIdx.x;
    int v = (tid < nb) ? blkSum[tid] : 0;
    s[tid] = v; __syncthreads();
    for (int off = 1; off < 512; off <<= 1) {
        int t = (tid >= off) ? s[tid - off] : 0;
        __syncthreads();
        s[tid] += t;
        __syncthreads();
    }
    blkOff[tid] = s[tid] - v;  // exclusive
}

__global__ void k_scanC(int* start, const int* blkOff, const int* deg,
                        float* dinv, int N) {
    int i = blockIdx.x * blockDim.x + threadIdx.x;
    if (i < N) {
        start[i] += blkOff[i >> 8];
        dinv[i] = rsqrtf((float)(deg[i] + 1));  // +1 self-loop
    }
}

// Atomic-free scatter: pos = start[dst] + rank (unique). 8 edges/thread ILP.
__launch_bounds__(256)
__global__ void k_scatter(const void* e, const int* __restrict__ start,
                          const int* __restrict__ rank, int* __restrict__ srcSorted,
                          const int* flags, int E) {
    int is64 = flags[0];
    int gsz = gridDim.x * blockDim.x;
    int i0 = blockIdx.x * blockDim.x + threadIdx.x;
    #pragma unroll
    for (int k = 0; k < 8; ++k) {
        int i = i0 + k * gsz;
        if (i < E) {
            int s = edgeIdx(e, i, is64);
            int d = edgeIdx(e, (long long)E + i, is64);
            srcSorted[start[d] + rank[i]] = s;
        }
    }
}

// h[N,64] = x[N,128] @ W1[128,64], f32 accumulate, f32 out to workspace.
// NOTE: h aliases rank[] — k_gemm must run after k_scatter (it does).
__launch_bounds__(256)
__global__ void k_gemm(const void* x, const void* W1, float* __restrict__ h,
                       const int* flags, int N) {
    __shared__ float Wl[128 * 64];   // 32 KB
    __shared__ float xr[4][128];     // one staged row per wave
    int tid = threadIdx.x;
    int isbf = flags[1];
    for (int idx = tid; idx < 128 * 64; idx += 256) Wl[idx] = loadF(W1, idx, isbf);
    int w = tid >> 6, lane = tid & 63;
    for (int rb = blockIdx.x * 4; rb < N; rb += gridDim.x * 4) {
        int row = rb + w;
        bool active = row < N;
        __syncthreads();
        if (active) {
            if (isbf) {
                unsigned int wv = ((const unsigned int*)x)[(long long)row * 64 + lane];
                xr[w][2 * lane]     = bf2f((unsigned short)(wv & 0xffffu));
                xr[w][2 * lane + 1] = bf2f((unsigned short)(wv >> 16));
            } else {
                xr[w][lane]      = ((const float*)x)[(long long)row * 128 + lane];
                xr[w][lane + 64] = ((const float*)x)[(long long)row * 128 + 64 + lane];
            }
        }
        __syncthreads();
        if (active) {
            float acc = 0.f;
            #pragma unroll
            for (int k = 0; k < 128; ++k)
                acc += xr[w][k] * Wl[k * 64 + lane];
            h[(long long)row * 64 + lane] = acc;
        }
    }
}

// Layer-1 aggregation + epilogue (bias, relu, dot W2, scale dinv) fused.
// One wave per node; lane = feature. sbuf2[i] = (relu(agg+b1)·W2) * dinv[i].
__launch_bounds__(256)
__global__ void k_agg1(const float* __restrict__ h, const float* __restrict__ dinv,
                       const int* __restrict__ start, const int* __restrict__ deg,
                       const int* __restrict__ srcSorted,
                       const void* b1, const void* W2, float* __restrict__ sbuf2,
                       const int* flags, int N) {
    int lane = threadIdx.x & 63;
    int node = (blockIdx.x * blockDim.x + threadIdx.x) >> 6;
    if (node >= N) return;
    int isbf = flags[1];
    float di = dinv[node];
    float acc = h[(long long)node * 64 + lane] * di * di;  // self-loop
    int base = start[node], cnt = deg[node];
    for (int c = 0; c < cnt; c += 64) {
        int t = c + lane;
        int sidx = 0; float dv = 0.f;
        if (t < cnt) { sidx = srcSorted[base + t]; dv = dinv[sidx]; }
        int m = cnt - c; if (m > 64) m = 64;
        for (int t2 = 0; t2 < m; ++t2) {
            int s2 = __shfl(sidx, t2);
            float wgt = __shfl(dv, t2) * di;
            acc += h[(long long)s2 * 64 + lane] * wgt;
        }
    }
    float v = acc + loadF(b1, lane, isbf);
    v = fmaxf(v, 0.f);
    float p = v * loadF(W2, lane, isbf);
    #pragma unroll
    for (int o = 32; o >= 1; o >>= 1) p += __shfl_xor(p, o);
    if (lane == 0) sbuf2[node] = p * di;
}

// Layer-2 scalar aggregation: out[i] = (sum_in sbuf2[src] + sbuf2[i]) * dinv[i] + b2
__launch_bounds__(256)
__global__ void k_agg2(const float* __restrict__ sbuf2, const float* __restrict__ dinv,
                       const int* __restrict__ start, const int* __restrict__ deg,
                       const int* __restrict__ srcSorted,
                       const void* b2, void* out, const int* flags, int N) {
    int lane = threadIdx.x & 63;
    int node = (blockIdx.x * blockDim.x + threadIdx.x) >> 6;
    if (node >= N) return;
    int isbf = flags[1];
    float di = dinv[node];
    int base = start[node], cnt = deg[node];
    float part = 0.f;
    for (int t = lane; t < cnt; t += 64) part += sbuf2[srcSorted[base + t]];
    #pragma unroll
    for (int o = 32; o >= 1; o >>= 1) part += __shfl_xor(part, o);
    if (lane == 0) {
        float o_ = (part + sbuf2[node]) * di + loadF(b2, 0, isbf);
        if (isbf) ((unsigned short*)out)[node] = f2bf(o_);
        else      ((float*)out)[node] = o_;
    }
}

extern "C" void kernel_launch(void* const* d_in, const int* in_sizes, int n_in,
                              void* d_out, int out_size, void* d_ws, size_t ws_size,
                              hipStream_t stream) {
    const void* x  = d_in[0];
    const void* e  = d_in[1];
    const void* W1 = d_in[2];
    const void* b1 = d_in[3];
    const void* W2 = d_in[4];
    const void* b2 = d_in[5];
    int N = in_sizes[0] / 128;   // 100000
    int E = in_sizes[1] / 2;     // 3200000
    int nb = (N + 255) / 256;    // 391 (<= 512 for scanB)
    int NP = nb * 256;
    int EP = ((E + 255) / 256) * 256;

    // Workspace layout (total ~40.0 MB, matches R1's proven footprint):
    int*   wsI       = (int*)d_ws;
    int*   flags     = wsI;                 // 256 ints
    int*   deg       = wsI + 256;           // NP
    int*   start     = deg + NP;            // NP
    float* dinv      = (float*)(start + NP);    // NP
    float* sbuf2     = dinv + NP;               // NP
    int*   blkSum    = (int*)(sbuf2 + NP);  // 512
    int*   blkOff    = blkSum + 512;        // 512
    int*   srcSorted = blkOff + 512;        // EP
    float* h         = (float*)(srcSorted + EP);  // N*64 floats (25.6 MB)
    int*   rank      = (int*)h;             // EP ints, ALIASES h (dead before k_gemm)

    hipMemsetAsync(deg, 0, (size_t)NP * sizeof(int), stream);
    hipLaunchKernelGGL(k_detect, dim3(1), dim3(64), 0, stream, e, x, flags);
    hipLaunchKernelGGL(k_count, dim3((E + 2047) / 2048), dim3(256), 0, stream,
                       e, deg, rank, flags, E);
    hipLaunchKernelGGL(k_scanA, dim3(nb), dim3(256), 0, stream, deg, start, blkSum, N);
    hipLaunchKernelGGL(k_scanB, dim3(1), dim3(512), 0, stream, blkSum, blkOff, nb);
    hipLaunchKernelGGL(k_scanC, dim3(nb), dim3(256), 0, stream,
                       start, blkOff, deg, dinv, N);
    hipLaunchKernelGGL(k_scatter, dim3((E + 2047) / 2048), dim3(256), 0, stream,
                       e, start, rank, srcSorted, flags, E);
    hipLaunchKernelGGL(k_gemm, dim3(2048), dim3(256), 0, stream, x, W1, h, flags, N);
    hipLaunchKernelGGL(k_agg1, dim3((N + 3) / 4), dim3(256), 0, stream,
                       h, dinv, start, deg, srcSorted, b1, W2, sbuf2, flags, N);
    hipLaunchKernelGGL(k_agg2, dim3((N + 3) / 4), dim3(256), 0, stream,
                       sbuf2, dinv, start, deg, srcSorted, b2, d_out, flags, N);
}

// Round 4
// 480.479 us; speedup vs baseline: 1.4649x; 1.2230x over previous
//
#include <hip/hip_runtime.h>
#include <hip/hip_bf16.h>

// GCN 2-layer on MI355X.
// Pipeline: detect dtypes -> degree count + per-edge rank (atomic return) ->
// exclusive scan (CSR starts) -> atomic-free scatter into CSR -> GEMM h=x@W1
// (h stored bf16) -> wave-per-node aggregation+epilogue (layer1 fused with
// layer2 GEMV) -> wave-per-node scalar aggregation (layer2).
// R2/R3: rank trick + 8-way ILP fixed count/scatter latency wall; rank aliases h.
// R4: k_agg1 was 194us = 1 gather outstanding/wave (900cy/edge, VALUBusy 27%).
//     Fix: 8-way unrolled gather batch (8 loads in flight) + h in bf16
//     (halves gather bytes: 256->128 B/edge, table 25.6->12.8 MB).

__device__ __forceinline__ float bf2f(unsigned short u) {
    union { unsigned int u; float f; } c; c.u = ((unsigned int)u) << 16; return c.f;
}
__device__ __forceinline__ unsigned short f2bf(float f) {
    union { float f; unsigned int u; } c; c.f = f;
    unsigned int u = c.u;
    unsigned int r = (u + 0x7fffu + ((u >> 16) & 1u)) >> 16;  // round-nearest-even
    return (unsigned short)r;
}
__device__ __forceinline__ float loadF(const void* p, int i, int isbf) {
    return isbf ? bf2f(((const unsigned short*)p)[i]) : ((const float*)p)[i];
}
__device__ __forceinline__ int edgeIdx(const void* e, long long i, int is64) {
    return is64 ? (int)((const long long*)e)[i] : ((const int*)e)[i];
}

// flags[0] = edge indices are int64; flags[1] = float tensors are bf16
__global__ void k_detect(const void* e, const void* x, int* flags) {
    int lane = threadIdx.x;  // blockDim = 64
    unsigned int ew = ((const unsigned int*)e)[2 * lane + 1];
    unsigned long long nz = __ballot(ew != 0);
    unsigned int xw = ((const unsigned int*)x)[lane];
    unsigned int low = xw & 0xffffu;
    unsigned int e8 = (low >> 7) & 0xffu;
    bool plaus = (low == 0u) || (e8 >= 110u && e8 <= 135u);
    unsigned long long pl = __ballot(plaus);
    if (lane == 0) {
        flags[0] = (nz == 0ull) ? 1 : 0;
        flags[1] = (__popcll(pl) > 32) ? 1 : 0;
    }
}

// Degree histogram + unique per-edge rank. 8 edges/thread ILP.
__launch_bounds__(256)
__global__ void k_count(const void* e, int* __restrict__ deg, int* __restrict__ rank,
                        const int* flags, int E) {
    int is64 = flags[0];
    int gsz = gridDim.x * blockDim.x;
    int i0 = blockIdx.x * blockDim.x + threadIdx.x;
    #pragma unroll
    for (int k = 0; k < 8; ++k) {
        int i = i0 + k * gsz;
        if (i < E) {
            int d = edgeIdx(e, (long long)E + i, is64);
            rank[i] = atomicAdd(&deg[d], 1);
        }
    }
}

__global__ void k_scanA(const int* deg, int* start, int* blkSum, int N) {
    __shared__ int s[256];
    int tid = threadIdx.x;
    int i = blockIdx.x * 256 + tid;
    int v = (i < N) ? deg[i] : 0;
    s[tid] = v; __syncthreads();
    for (int off = 1; off < 256; off <<= 1) {
        int t = (tid >= off) ? s[tid - off] : 0;
        __syncthreads();
        s[tid] += t;
        __syncthreads();
    }
    if (i < N) start[i] = s[tid] - v;
    if (tid == 255) blkSum[blockIdx.x] = s[255];
}

__global__ void k_scanB(const int* blkSum, int* blkOff, int nb) {
    __shared__ int s[512];
    int tid = threadIdx.x;
    int v = (tid < nb) ? blkSum[tid] : 0;
    s[tid] = v; __syncthreads();
    for (int off = 1; off < 512; off <<= 1) {
        int t = (tid >= off) ? s[tid - off] : 0;
        __syncthreads();
        s[tid] += t;
        __syncthreads();
    }
    blkOff[tid] = s[tid] - v;
}

__global__ void k_scanC(int* start, const int* blkOff, const int* deg,
                        float* dinv, int N) {
    int i = blockIdx.x * blockDim.x + threadIdx.x;
    if (i < N) {
        start[i] += blkOff[i >> 8];
        dinv[i] = rsqrtf((float)(deg[i] + 1));  // +1 self-loop
    }
}

// Atomic-free scatter: pos = start[dst] + rank. 8 edges/thread ILP.
__launch_bounds__(256)
__global__ void k_scatter(const void* e, const int* __restrict__ start,
                          const int* __restrict__ rank, int* __restrict__ srcSorted,
                          const int* flags, int E) {
    int is64 = flags[0];
    int gsz = gridDim.x * blockDim.x;
    int i0 = blockIdx.x * blockDim.x + threadIdx.x;
    #pragma unroll
    for (int k = 0; k < 8; ++k) {
        int i = i0 + k * gsz;
        if (i < E) {
            int s = edgeIdx(e, i, is64);
            int d = edgeIdx(e, (long long)E + i, is64);
            srcSorted[start[d] + rank[i]] = s;
        }
    }
}

// h[N,64] = x[N,128] @ W1[128,64], f32 accumulate, stored as bf16.
// NOTE: hb aliases rank[] — k_gemm must run after k_scatter (it does).
__launch_bounds__(256)
__global__ void k_gemm(const void* x, const void* W1, unsigned short* __restrict__ hb,
                       const int* flags, int N) {
    __shared__ float Wl[128 * 64];   // 32 KB
    __shared__ float xr[4][128];
    int tid = threadIdx.x;
    int isbf = flags[1];
    for (int idx = tid; idx < 128 * 64; idx += 256) Wl[idx] = loadF(W1, idx, isbf);
    int w = tid >> 6, lane = tid & 63;
    for (int rb = blockIdx.x * 4; rb < N; rb += gridDim.x * 4) {
        int row = rb + w;
        bool active = row < N;
        __syncthreads();
        if (active) {
            if (isbf) {
                unsigned int wv = ((const unsigned int*)x)[(long long)row * 64 + lane];
                xr[w][2 * lane]     = bf2f((unsigned short)(wv & 0xffffu));
                xr[w][2 * lane + 1] = bf2f((unsigned short)(wv >> 16));
            } else {
                xr[w][lane]      = ((const float*)x)[(long long)row * 128 + lane];
                xr[w][lane + 64] = ((const float*)x)[(long long)row * 128 + 64 + lane];
            }
        }
        __syncthreads();
        if (active) {
            float acc = 0.f;
            #pragma unroll
            for (int k = 0; k < 128; ++k)
                acc += xr[w][k] * Wl[k * 64 + lane];
            hb[(long long)row * 64 + lane] = f2bf(acc);
        }
    }
}

// Layer-1 aggregation + epilogue (bias, relu, dot W2, scale dinv) fused.
// One wave per node; lane = feature. 8-way unrolled gather batch for ILP.
__launch_bounds__(256)
__global__ void k_agg1(const unsigned short* __restrict__ hb,
                       const float* __restrict__ dinv,
                       const int* __restrict__ start, const int* __restrict__ deg,
                       const int* __restrict__ srcSorted,
                       const void* b1, const void* W2, float* __restrict__ sbuf2,
                       const int* flags, int N) {
    int lane = threadIdx.x & 63;
    int node = (blockIdx.x * blockDim.x + threadIdx.x) >> 6;
    if (node >= N) return;
    int isbf = flags[1];
    float di = dinv[node];
    float acc = bf2f(hb[(long long)node * 64 + lane]) * di * di;  // self-loop
    int base = start[node], cnt = deg[node];
    for (int c = 0; c < cnt; c += 64) {
        int t = c + lane;
        int sidx = 0; float dv = 0.f;
        if (t < cnt) { sidx = srcSorted[base + t]; dv = dinv[sidx] * di; }
        int m = cnt - c; if (m > 64) m = 64;
        int t2 = 0;
        for (; t2 + 8 <= m; t2 += 8) {
            int s0 = __shfl(sidx, t2 + 0), s1 = __shfl(sidx, t2 + 1);
            int s2 = __shfl(sidx, t2 + 2), s3 = __shfl(sidx, t2 + 3);
            int s4 = __shfl(sidx, t2 + 4), s5 = __shfl(sidx, t2 + 5);
            int s6 = __shfl(sidx, t2 + 6), s7 = __shfl(sidx, t2 + 7);
            float w0 = __shfl(dv, t2 + 0), w1 = __shfl(dv, t2 + 1);
            float w2 = __shfl(dv, t2 + 2), w3 = __shfl(dv, t2 + 3);
            float w4 = __shfl(dv, t2 + 4), w5 = __shfl(dv, t2 + 5);
            float w6 = __shfl(dv, t2 + 6), w7 = __shfl(dv, t2 + 7);
            // 8 independent gathers in flight
            unsigned short v0 = hb[(long long)s0 * 64 + lane];
            unsigned short v1 = hb[(long long)s1 * 64 + lane];
            unsigned short v2 = hb[(long long)s2 * 64 + lane];
            unsigned short v3 = hb[(long long)s3 * 64 + lane];
            unsigned short v4 = hb[(long long)s4 * 64 + lane];
            unsigned short v5 = hb[(long long)s5 * 64 + lane];
            unsigned short v6 = hb[(long long)s6 * 64 + lane];
            unsigned short v7 = hb[(long long)s7 * 64 + lane];
            acc += bf2f(v0) * w0; acc += bf2f(v1) * w1;
            acc += bf2f(v2) * w2; acc += bf2f(v3) * w3;
            acc += bf2f(v4) * w4; acc += bf2f(v5) * w5;
            acc += bf2f(v6) * w6; acc += bf2f(v7) * w7;
        }
        for (; t2 < m; ++t2) {
            int s0 = __shfl(sidx, t2);
            float w0 = __shfl(dv, t2);
            acc += bf2f(hb[(long long)s0 * 64 + lane]) * w0;
        }
    }
    float v = acc + loadF(b1, lane, isbf);
    v = fmaxf(v, 0.f);
    float p = v * loadF(W2, lane, isbf);
    #pragma unroll
    for (int o = 32; o >= 1; o >>= 1) p += __shfl_xor(p, o);
    if (lane == 0) sbuf2[node] = p * di;
}

// Layer-2 scalar aggregation: out[i] = (sum_in sbuf2[src] + sbuf2[i]) * dinv[i] + b2
__launch_bounds__(256)
__global__ void k_agg2(const float* __restrict__ sbuf2, const float* __restrict__ dinv,
                       const int* __restrict__ start, const int* __restrict__ deg,
                       const int* __restrict__ srcSorted,
                       const void* b2, void* out, const int* flags, int N) {
    int lane = threadIdx.x & 63;
    int node = (blockIdx.x * blockDim.x + threadIdx.x) >> 6;
    if (node >= N) return;
    int isbf = flags[1];
    float di = dinv[node];
    int base = start[node], cnt = deg[node];
    float part = 0.f;
    for (int t = lane; t < cnt; t += 64) part += sbuf2[srcSorted[base + t]];
    #pragma unroll
    for (int o = 32; o >= 1; o >>= 1) part += __shfl_xor(part, o);
    if (lane == 0) {
        float o_ = (part + sbuf2[node]) * di + loadF(b2, 0, isbf);
        if (isbf) ((unsigned short*)out)[node] = f2bf(o_);
        else      ((float*)out)[node] = o_;
    }
}

extern "C" void kernel_launch(void* const* d_in, const int* in_sizes, int n_in,
                              void* d_out, int out_size, void* d_ws, size_t ws_size,
                              hipStream_t stream) {
    const void* x  = d_in[0];
    const void* e  = d_in[1];
    const void* W1 = d_in[2];
    const void* b1 = d_in[3];
    const void* W2 = d_in[4];
    const void* b2 = d_in[5];
    int N = in_sizes[0] / 128;   // 100000
    int E = in_sizes[1] / 2;     // 3200000
    int nb = (N + 255) / 256;    // 391 (<= 512 for scanB)
    int NP = nb * 256;
    int EP = ((E + 255) / 256) * 256;

    // Workspace layout (~27.2 MB):
    int*   wsI       = (int*)d_ws;
    int*   flags     = wsI;                 // 256 ints
    int*   deg       = wsI + 256;           // NP
    int*   start     = deg + NP;            // NP
    float* dinv      = (float*)(start + NP);    // NP
    float* sbuf2     = dinv + NP;               // NP
    int*   blkSum    = (int*)(sbuf2 + NP);  // 512
    int*   blkOff    = blkSum + 512;        // 512
    int*   srcSorted = blkOff + 512;        // EP
    unsigned short* hb = (unsigned short*)(srcSorted + EP);  // N*64 bf16 (12.8 MB)
    int*   rank      = (int*)hb;            // EP ints, ALIASES hb (dead before k_gemm)

    hipMemsetAsync(deg, 0, (size_t)NP * sizeof(int), stream);
    hipLaunchKernelGGL(k_detect, dim3(1), dim3(64), 0, stream, e, x, flags);
    hipLaunchKernelGGL(k_count, dim3((E + 2047) / 2048), dim3(256), 0, stream,
                       e, deg, rank, flags, E);
    hipLaunchKernelGGL(k_scanA, dim3(nb), dim3(256), 0, stream, deg, start, blkSum, N);
    hipLaunchKernelGGL(k_scanB, dim3(1), dim3(512), 0, stream, blkSum, blkOff, nb);
    hipLaunchKernelGGL(k_scanC, dim3(nb), dim3(256), 0, stream,
                       start, blkOff, deg, dinv, N);
    hipLaunchKernelGGL(k_scatter, dim3((E + 2047) / 2048), dim3(256), 0, stream,
                       e, start, rank, srcSorted, flags, E);
    hipLaunchKernelGGL(k_gemm, dim3(2048), dim3(256), 0, stream, x, W1, hb, flags, N);
    hipLaunchKernelGGL(k_agg1, dim3((N + 3) / 4), dim3(256), 0, stream,
                       hb, dinv, start, deg, srcSorted, b1, W2, sbuf2, flags, N);
    hipLaunchKernelGGL(k_agg2, dim3((N + 3) / 4), dim3(256), 0, stream,
                       sbuf2, dinv, start, deg, srcSorted, b2, d_out, flags, N);
}